// Round 15
// baseline (84.923 us; speedup 1.0000x reference)
//
#include <hip/hip_runtime.h>

#define LOG2E 1.4426950408889634f
#define LN2   0.6931471805599453

static constexpr int B  = 32;
static constexpr int T  = 1024;   // original time length; we use rows 0..1022
static constexpr int TT = 1023;   // T-1
static constexpr int V  = 1000;
static constexpr int L  = 256;    // padded target length; labels used are cols 1..255
static constexpr int S  = 511;    // 2*255+1 extended states (valid s: 0..510)
static constexpr int SP = 512;    // padded state stride (slot 511 == 0)
static constexpr int TP = 1024;   // padded rows per batch in E

using h8  = __attribute__((ext_vector_type(8))) _Float16;
using hf2 = __attribute__((ext_vector_type(2))) __fp16;   // cvt_pkrtz return type
using f4  = __attribute__((ext_vector_type(4))) float;
using i4  = __attribute__((ext_vector_type(4))) int;

__device__ __forceinline__ float fexp2(float x) {
#if __has_builtin(__builtin_amdgcn_exp2f)
  return __builtin_amdgcn_exp2f(x);
#else
  return exp2f(x);
#endif
}
__device__ __forceinline__ float flog2(float x) {
#if __has_builtin(__builtin_amdgcn_logf)
  return __builtin_amdgcn_logf(x);   // v_log_f32 = log base 2
#else
  return log2f(x);
#endif
}

// ---- DPP helpers (VALU cross-lane; no LDS) ------------------------------
#if __has_builtin(__builtin_amdgcn_update_dpp)
// wave_shr1: lane i <- lane i-1; lane 0 <- 0 (bound_ctrl)
__device__ __forceinline__ float shr1f(float x) {
  int r = __builtin_amdgcn_update_dpp(0, __float_as_int(x), 0x138, 0xf, 0xf, true);
  return __int_as_float(r);
}
// wave_shl1: lane i <- lane i+1; lane 63 <- 0 (bound_ctrl)
__device__ __forceinline__ int shl1i(int x) {
  return __builtin_amdgcn_update_dpp(0, x, 0x130, 0xf, 0xf, true);
}
#define DPP_SWITCH(T, OLD, SRC, BC)                                            \
  T r;                                                                         \
  switch (ctrl) {                                                              \
    case 0x111: r = __builtin_amdgcn_update_dpp(OLD, SRC, 0x111, 0xf, 0xf, BC); break; \
    case 0x112: r = __builtin_amdgcn_update_dpp(OLD, SRC, 0x112, 0xf, 0xf, BC); break; \
    case 0x114: r = __builtin_amdgcn_update_dpp(OLD, SRC, 0x114, 0xf, 0xf, BC); break; \
    case 0x118: r = __builtin_amdgcn_update_dpp(OLD, SRC, 0x118, 0xf, 0xf, BC); break; \
    case 0x142: r = __builtin_amdgcn_update_dpp(OLD, SRC, 0x142, 0xf, 0xf, BC); break; \
    default:    r = __builtin_amdgcn_update_dpp(OLD, SRC, 0x143, 0xf, 0xf, BC); break; \
  }

// int max step, 0-identity (nonneg values only)
__device__ __forceinline__ int dppmax_step(int m, const int ctrl) {
  DPP_SWITCH(int, 0, m, true);
  return max(m, r);
}
__device__ __forceinline__ int wavemax_to_sgpr(int m) {
  m = dppmax_step(m, 0x111);
  m = dppmax_step(m, 0x112);
  m = dppmax_step(m, 0x114);
  m = dppmax_step(m, 0x118);
  m = dppmax_step(m, 0x142);
  m = dppmax_step(m, 0x143);
  return __builtin_amdgcn_readlane(m, 63);
}
// float max step, identity-free: invalid lanes keep old (=x) -> fmax(x,x)=x
__device__ __forceinline__ float dppfmax_step(float x, const int ctrl) {
  int xi = __float_as_int(x);
  DPP_SWITCH(int, xi, xi, false);
  return fmaxf(x, __int_as_float(r));
}
__device__ __forceinline__ float wavefmax(float x) {
  x = dppfmax_step(x, 0x111);
  x = dppfmax_step(x, 0x112);
  x = dppfmax_step(x, 0x114);
  x = dppfmax_step(x, 0x118);
  x = dppfmax_step(x, 0x142);
  x = dppfmax_step(x, 0x143);
  return __int_as_float(__builtin_amdgcn_readlane(__float_as_int(x), 63));
}
// float add step, 0-identity
__device__ __forceinline__ float dppfadd_step(float x, const int ctrl) {
  DPP_SWITCH(int, 0, __float_as_int(x), true);
  return x + __int_as_float(r);
}
__device__ __forceinline__ float wavefsum(float x) {
  x = dppfadd_step(x, 0x111);
  x = dppfadd_step(x, 0x112);
  x = dppfadd_step(x, 0x114);
  x = dppfadd_step(x, 0x118);
  x = dppfadd_step(x, 0x142);
  x = dppfadd_step(x, 0x143);
  return __int_as_float(__builtin_amdgcn_readlane(__float_as_int(x), 63));
}
#else
__device__ __forceinline__ float shr1f(float x) {
  float r = __shfl_up(x, 1, 64);
  return (threadIdx.x & 63) == 0 ? 0.0f : r;
}
__device__ __forceinline__ int shl1i(int x) {
  int r = __shfl_down(x, 1, 64);
  return (threadIdx.x & 63) == 63 ? 0 : r;
}
__device__ __forceinline__ int wavemax_to_sgpr(int m) {
  for (int o = 32; o >= 1; o >>= 1) m = max(m, __shfl_xor(m, o, 64));
  return m;
}
__device__ __forceinline__ float wavefmax(float x) {
  for (int o = 32; o >= 1; o >>= 1) x = fmaxf(x, __shfl_xor(x, o, 64));
  return x;
}
__device__ __forceinline__ float wavefsum(float x) {
  for (int o = 32; o >= 1; o >>= 1) x += __shfl_xor(x, o, 64);
  return x;
}
#endif

// ---- target length from padding mask (byte-bool vs int32 hedge) ---------
// One wave. Byte-count of a bool batch lies in [130,256]; of int32 <=64.
__device__ __forceinline__ int mask_tlen(const unsigned char* maskb, int b, int lane) {
  int ca = 0;
  for (int k = lane; k < L; k += 64) ca += (maskb[b * L + k] != 0) ? 1 : 0;
  for (int o = 32; o >= 1; o >>= 1) ca += __shfl_xor(ca, o, 64);
  int cnt = ca;
  if (ca < 130) {  // wave-uniform: layout must be int32
    const int* mi = (const int*)maskb;
    int cb = 0;
    for (int k = lane; k < L; k += 64) cb += (mi[b * L + k] != 0) ? 1 : 0;
    for (int o = 32; o >= 1; o >>= 1) cb += __shfl_xor(cb, o, 64);
    cnt = cb;
  }
  return cnt - 1;
}

// ---------------- K1: wave-per-row softmax-scale + emit gather -----------
// One WAVE per (b,t) row; DPP-only reductions; per-wave private LDS row.
// NO validity masking here: invalid states never feed valid ones (CTC
// transitions are monotone in s); k_ctc's RESCALE masks them out of the
// wave-max so the scaling window tracks the VALID states.
// E[b][t][s] = fp16( 2^((y[ext_s]-rowmax)*log2e) ); slot 511 = 0.
// G[r] = rowmax*log2e - lse2 = -log2( sum 2^((y-rowmax)*log2e) ).
__global__ __launch_bounds__(256) void k_emit(const float* __restrict__ logits,
                                              const int* __restrict__ targets,
                                              _Float16* __restrict__ E,
                                              float* __restrict__ G) {
  __shared__ float yrow[4][1024];  // 16KB: per-wave private raw-logit row
  const int wid = threadIdx.x >> 6;
  const int lane = threadIdx.x & 63;
  float* yw = yrow[wid];
  const int r = blockIdx.x * 4 + wid;   // B*TT = 32736 = 8184 * 4 exactly
  const int b = r / TT;
  const int t = r - b * TT;

  const f4* row = reinterpret_cast<const f4*>(logits + ((size_t)b * T + t) * V);
  f4 u0 = row[lane];
  f4 u1 = row[lane + 64];
  f4 u2 = row[lane + 128];
  const bool has3 = (lane < 58);  // 1000 = 250 float4
  f4 u3;
  if (has3) u3 = row[lane + 192];
  else { u3[0] = u3[1] = u3[2] = u3[3] = -3.0e38f; }

  reinterpret_cast<f4*>(yw)[lane]       = u0;
  reinterpret_cast<f4*>(yw)[lane + 64]  = u1;
  reinterpret_cast<f4*>(yw)[lane + 128] = u2;
  if (has3) reinterpret_cast<f4*>(yw)[lane + 192] = u3;

  float lm = fmaxf(fmaxf(fmaxf(u0[0], u0[1]), fmaxf(u0[2], u0[3])),
                   fmaxf(fmaxf(u1[0], u1[1]), fmaxf(u1[2], u1[3])));
  lm = fmaxf(lm, fmaxf(fmaxf(u2[0], u2[1]), fmaxf(u2[2], u2[3])));
  lm = fmaxf(lm, fmaxf(fmaxf(u3[0], u3[1]), fmaxf(u3[2], u3[3])));
  const float my = wavefmax(lm);        // raw-domain row max (uniform)
  const float c = -my * LOG2E;          // exp2(x*LOG2E + c) = 2^((x-my)*log2e)

  float ps = fexp2(fmaf(u0[0], LOG2E, c)) + fexp2(fmaf(u0[1], LOG2E, c))
           + fexp2(fmaf(u0[2], LOG2E, c)) + fexp2(fmaf(u0[3], LOG2E, c))
           + fexp2(fmaf(u1[0], LOG2E, c)) + fexp2(fmaf(u1[1], LOG2E, c))
           + fexp2(fmaf(u1[2], LOG2E, c)) + fexp2(fmaf(u1[3], LOG2E, c))
           + fexp2(fmaf(u2[0], LOG2E, c)) + fexp2(fmaf(u2[1], LOG2E, c))
           + fexp2(fmaf(u2[2], LOG2E, c)) + fexp2(fmaf(u2[3], LOG2E, c))
           + fexp2(fmaf(u3[0], LOG2E, c)) + fexp2(fmaf(u3[1], LOG2E, c))
           + fexp2(fmaf(u3[2], LOG2E, c)) + fexp2(fmaf(u3[3], LOG2E, c));
  const float g = -flog2(wavefsum(ps)); // rowmax - lse (log2 domain)

  // gather: lane l -> states 8l..8l+7; labels 4l+1..4l+4 (int4 + DPP shl)
  const int base = b * L + (lane << 2);
  i4 tv = *reinterpret_cast<const i4*>(targets + base);  // 16B-aligned
  const int l1 = tv[1], l2 = tv[2], l3 = tv[3];
  const int l4 = shl1i(tv[0]);          // label 4l+4 from lane+1; lane63 -> 0
  const float eb = fexp2(fmaf(yw[0],  LOG2E, c));
  const float e1 = fexp2(fmaf(yw[l1], LOG2E, c));
  const float e2 = fexp2(fmaf(yw[l2], LOG2E, c));
  const float e3 = fexp2(fmaf(yw[l3], LOG2E, c));
  float e4       = fexp2(fmaf(yw[l4], LOG2E, c));
  if (lane == 63) e4 = 0.0f;            // slot 511 (dead state) must be 0

#if __has_builtin(__builtin_amdgcn_cvt_pkrtz)
  i4 oi;
  { hf2 p = __builtin_amdgcn_cvt_pkrtz(eb, e1); oi[0] = __builtin_bit_cast(int, p); }
  { hf2 p = __builtin_amdgcn_cvt_pkrtz(eb, e2); oi[1] = __builtin_bit_cast(int, p); }
  { hf2 p = __builtin_amdgcn_cvt_pkrtz(eb, e3); oi[2] = __builtin_bit_cast(int, p); }
  { hf2 p = __builtin_amdgcn_cvt_pkrtz(eb, e4); oi[3] = __builtin_bit_cast(int, p); }
  reinterpret_cast<i4*>(E + ((size_t)b * TP + t) * SP)[lane] = oi;
#else
  h8 o;
  o[0] = (_Float16)eb; o[1] = (_Float16)e1;
  o[2] = (_Float16)eb; o[3] = (_Float16)e2;
  o[4] = (_Float16)eb; o[5] = (_Float16)e3;
  o[6] = (_Float16)eb; o[7] = (_Float16)e4;
  reinterpret_cast<h8*>(E + ((size_t)b * TP + t) * SP)[lane] = o;
#endif
  if (lane == 0) G[r] = g;
}

// ---------------- K2: CTC alpha recurrence, f32 prob domain --------------
// One wave per batch; lane l owns states 8l..8l+7. E rows fp16, consumed via
// v_fma_mix_f32. Inline-asm load pipeline: SIX buffers x 8 rows (48 rows /
// 48 loads in flight, ~1800 cy of compute cover vs ~900 cy worst latency),
// counted s_waitcnt vmcnt(40). Exact pow2 rescale (VALID-state wave max ->
// 2^76) every 24 steps; invalid states (s > 2*tl) masked out of the max.
// G-sum deferred to the epilogue so its loads never touch loop vmcnt.
__global__ __launch_bounds__(64, 1) void k_ctc(const _Float16* __restrict__ E,
                                               const int* __restrict__ targets,
                                               const unsigned char* __restrict__ maskb,
                                               const float* __restrict__ G,
                                               float* __restrict__ lossb) {
  const int b = blockIdx.x;
  const int lane = threadIdx.x;
  const int s0 = lane << 3;
  const int* tg = targets + b * L;

  const int tl = mask_tlen(maskb, b, lane);

  // skip-allowed multipliers for odd states (1.0f or 0.0f)
  float f1 = 0.0f, f3, f5, f7 = 0.0f;
  {
    int s = s0 + 1;
    if (s >= 3) f1 = (tg[(s + 1) >> 1] != tg[(s - 1) >> 1]) ? 1.0f : 0.0f;
    s = s0 + 3;
    f3 = (tg[(s + 1) >> 1] != tg[(s - 1) >> 1]) ? 1.0f : 0.0f;
    s = s0 + 5;
    f5 = (tg[(s + 1) >> 1] != tg[(s - 1) >> 1]) ? 1.0f : 0.0f;
    s = s0 + 7;
    if (s < S) f7 = (tg[(s + 1) >> 1] != tg[(s - 1) >> 1]) ? 1.0f : 0.0f;
  }

  // validity masks for the rescale max: state s0+i valid iff s0+i <= 2*tl
  const int s2t = 2 * tl;
  const int vm0 = (s0 + 0 <= s2t) ? -1 : 0;
  const int vm1 = (s0 + 1 <= s2t) ? -1 : 0;
  const int vm2 = (s0 + 2 <= s2t) ? -1 : 0;
  const int vm3 = (s0 + 3 <= s2t) ? -1 : 0;
  const int vm4 = (s0 + 4 <= s2t) ? -1 : 0;
  const int vm5 = (s0 + 5 <= s2t) ? -1 : 0;
  const int vm6 = (s0 + 6 <= s2t) ? -1 : 0;
  const int vm7 = (s0 + 7 <= s2t) ? -1 : 0;

  const _Float16* E0 = E + (size_t)b * TP * SP;
  const _Float16* Ebase = E0 + s0;   // row r starts at Ebase + r*SP (per-lane)

  // alpha init from t=0: only s=0,1 live
  float a0 = (lane == 0) ? (float)E0[0] : 0.0f;
  float a1 = (lane == 0) ? (float)E0[1] : 0.0f;
  float a2 = 0.f, a3 = 0.f, a4 = 0.f, a5 = 0.f, a6 = 0.f, a7 = 0.f;
  float n7 = 0.0f;  // a7 of lane-1, pipelined across steps
  int lsacc = 0;

  // Force all compiler-issued loads (mask, tg flags, E0[0..1]) to complete
  // NOW so the compiler never inserts its own s_waitcnt vmcnt(0) in the loop.
  asm volatile("" :: "v"(f1), "v"(f3), "v"(f5), "v"(f7),
                     "v"(a0), "v"(a1), "v"((float)tl));

// one row = 16B/lane; 4 rows per asm via offset immediates (row stride 1024B)
#define GLROW4(d0, d1, d2, d3, p)                                \
  asm volatile("global_load_dwordx4 %0, %4, off\n\t"             \
               "global_load_dwordx4 %1, %4, off offset:1024\n\t" \
               "global_load_dwordx4 %2, %4, off offset:2048\n\t" \
               "global_load_dwordx4 %3, %4, off offset:3072"     \
               : "=&v"(d0), "=&v"(d1), "=&v"(d2), "=&v"(d3) : "v"(p))

#define LOAD8(P, r0)                                             \
  do {                                                           \
    const _Float16* q_ = Ebase + (size_t)(r0) * SP;              \
    GLROW4(P##0, P##1, P##2, P##3, q_);                          \
    GLROW4(P##4, P##5, P##6, P##7, q_ + 4 * SP);                 \
  } while (0)

// counted wait; redefines buffer P's registers so uses can't precede it
#define VMWAIT8(n, P)                                            \
  do {                                                           \
    asm volatile("s_waitcnt vmcnt(" #n ")"                       \
                 : "+v"(P##0), "+v"(P##1), "+v"(P##2), "+v"(P##3), \
                   "+v"(P##4), "+v"(P##5), "+v"(P##6), "+v"(P##7)); \
    __builtin_amdgcn_sched_barrier(0);                           \
  } while (0)

// fused f16->f32 convert + multiply: D = s * f16(hw half) + 0
#define MIXLO(D, SSS, HWORD)                                     \
  asm("v_fma_mix_f32 %0, %1, %2, 0 op_sel:[0,0,0] op_sel_hi:[0,1,0]" \
      : "=v"(D) : "v"(SSS), "v"(HWORD))
#define MIXHI(D, SSS, HWORD)                                     \
  asm("v_fma_mix_f32 %0, %1, %2, 0 op_sel:[0,1,0] op_sel_hi:[0,1,0]" \
      : "=v"(D) : "v"(SSS), "v"(HWORD))

// One time step from one fp16 row. t7 first, its DPP issued immediately.
#define STEPF(H)                                                \
  do {                                                          \
    i4 hw = __builtin_bit_cast(i4, (H));                        \
    float s7 = fmaf(f7, a5, a6 + a7);                           \
    float t7; MIXHI(t7, s7, hw[3]);                             \
    float n7n = shr1f(t7);                                      \
    float s0_ = a0 + n7;                                        \
    float s1_ = fmaf(f1, n7, a0 + a1);                          \
    float s2_ = a1 + a2;                                        \
    float s3_ = fmaf(f3, a1, a2 + a3);                          \
    float s4_ = a3 + a4;                                        \
    float s5_ = fmaf(f5, a3, a4 + a5);                          \
    float s6_ = a5 + a6;                                        \
    float t0, t1, t2, t3, t4, t5, t6;                           \
    MIXLO(t0, s0_, hw[0]);                                      \
    MIXHI(t1, s1_, hw[0]);                                      \
    MIXLO(t2, s2_, hw[1]);                                      \
    MIXHI(t3, s3_, hw[1]);                                      \
    MIXLO(t4, s4_, hw[2]);                                      \
    MIXHI(t5, s5_, hw[2]);                                      \
    MIXLO(t6, s6_, hw[3]);                                      \
    a0 = t0; a1 = t1; a2 = t2; a3 = t3;                         \
    a4 = t4; a5 = t5; a6 = t6; a7 = t7;                         \
    n7 = n7n;                                                   \
  } while (0)

// exact pow2 rescale: VALID-state wave-max alpha -> 2^76, every 24 steps.
// Growth <= 3^24 ~ 2^38 per 24 steps; 2^77 * 2^38 = 2^115 < 2^127 (no
// overflow of valid states). Underflow window: 76+149 = 225 log2 (~156
// nats) below the valid max. Invalid states are masked out of the max.
#define RESCALE()                                               \
  do {                                                          \
    int m = max(max(max(__float_as_int(a0) & vm0,               \
                        __float_as_int(a1) & vm1),              \
                    max(__float_as_int(a2) & vm2,               \
                        __float_as_int(a3) & vm3)),             \
                max(max(__float_as_int(a4) & vm4,               \
                        __float_as_int(a5) & vm5),              \
                    max(__float_as_int(a6) & vm6,               \
                        __float_as_int(a7) & vm7)));            \
    int mw = wavemax_to_sgpr(m);                                \
    int e = mw >> 23;                                           \
    int sh = 203 - e;                                           \
    lsacc += e - 203;                                           \
    a0 = ldexpf(a0, sh); a1 = ldexpf(a1, sh);                   \
    a2 = ldexpf(a2, sh); a3 = ldexpf(a3, sh);                   \
    a4 = ldexpf(a4, sh); a5 = ldexpf(a5, sh);                   \
    a6 = ldexpf(a6, sh); a7 = ldexpf(a7, sh);                   \
    n7 = ldexpf(n7, sh);                                        \
  } while (0)

#define PROC8(P)                                                \
  do {                                                          \
    STEPF(P##0); STEPF(P##1); STEPF(P##2); STEPF(P##3);         \
    STEPF(P##4); STEPF(P##5); STEPF(P##6); STEPF(P##7);         \
  } while (0)

  h8 A0, A1, A2, A3, A4, A5, A6, A7;
  h8 B0, B1, B2, B3, B4, B5, B6, B7;
  h8 C0, C1, C2, C3, C4, C5, C6, C7;
  h8 D0, D1, D2, D3, D4, D5, D6, D7;
  h8 E0r, E1, E2, E3, E4, E5, E6, E7;
  h8 F0, F1, F2, F3, F4, F5, F6, F7;
  // (E buffer regs named E0r.. to avoid clash with pointer E0)
#define E0 E0r

  LOAD8(A, 1);    // rows 1..8     (8 loads)
  LOAD8(B, 9);    // rows 9..16    (16)
  LOAD8(C, 17);   // rows 17..24   (24)
  LOAD8(D, 25);   // rows 25..32   (32)
  LOAD8(E, 33);   // rows 33..40   (40)
  LOAD8(F, 41);   // rows 41..48   (48 outstanding)

  int t = 1;
#pragma unroll 1
  for (int it = 0; it < 20; ++it) {   // 20 * 48 = 960 rows: t = 1 .. 960
    RESCALE();                        // every 24 steps (here + mid-iter)
    VMWAIT8(40, A); PROC8(A); LOAD8(A, t + 48);
    VMWAIT8(40, B); PROC8(B); LOAD8(B, t + 56);
    VMWAIT8(40, C); PROC8(C); LOAD8(C, t + 64);
    RESCALE();
    VMWAIT8(40, D); PROC8(D); LOAD8(D, t + 72);
    VMWAIT8(40, E); PROC8(E); LOAD8(E, t + 80);
    VMWAIT8(40, F); PROC8(F); LOAD8(F, t + 88);
    t += 48;
  }
  // t = 961. In flight: A=961..968 .. F=1001..1008 (48 loads).
  RESCALE();
  VMWAIT8(40, A); PROC8(A); LOAD8(A, 1009);   // rows 961..968
  VMWAIT8(40, B); PROC8(B); LOAD8(B, 1017);   // rows 969..976
  VMWAIT8(40, C); PROC8(C);                   // rows 977..984
  RESCALE();
  VMWAIT8(32, D); PROC8(D);                   // rows 985..992
  VMWAIT8(24, E); PROC8(E);                   // rows 993..1000
  VMWAIT8(16, F); PROC8(F);                   // rows 1001..1008
  RESCALE();
  VMWAIT8(8,  A); PROC8(A);                   // rows 1009..1016
  VMWAIT8(0,  B);
  STEPF(B0); STEPF(B1); STEPF(B2);
  STEPF(B3); STEPF(B4); STEPF(B5);            // rows 1017..1022
#undef E0
#undef GLROW4
#undef LOAD8
#undef VMWAIT8
#undef MIXLO
#undef MIXHI
#undef STEPF
#undef RESCALE
#undef PROC8

  // per-batch sum of G (deterministic fixed tree, f64) — deferred to the
  // epilogue so its loads never interfere with the loop's vmcnt counts.
  double gs = 0.0;
  for (int k = lane; k < TT; k += 64) gs += (double)G[b * TT + k];
  for (int o = 32; o >= 1; o >>= 1) gs += __shfl_xor(gs, o, 64);

  // epilogue: pick states i1 and i1-1 via uniform reg-switch + shfl
  {
    int i1 = 2 * tl;
    int j1 = (i1 > 0 ? i1 : 1) - 1;
    float va, vb;
    switch (i1 & 7) {   // tl is wave-uniform -> uniform branch
      case 0: va = a0; break; case 1: va = a1; break;
      case 2: va = a2; break; case 3: va = a3; break;
      case 4: va = a4; break; case 5: va = a5; break;
      case 6: va = a6; break; default: va = a7; break;
    }
    switch (j1 & 7) {
      case 0: vb = a0; break; case 1: vb = a1; break;
      case 2: vb = a2; break; case 3: vb = a3; break;
      case 4: vb = a4; break; case 5: vb = a5; break;
      case 6: vb = a6; break; default: vb = a7; break;
    }
    float l1v = __shfl(va, i1 >> 3, 64);
    float l2v = __shfl(vb, j1 >> 3, 64);
    if (lane == 0) {
      float p = l1v + l2v;
      int hi = __float_as_int(p);
      int ep = (hi >> 23) - 127;
      float pm = ldexpf(p, -ep);          // in [1,2) for normal p
      float lm = flog2(pm);
      double loss2 = -((double)lm + (double)ep + (double)lsacc + gs);
      float loss = (float)(loss2 * LN2);  // back to natural log
      if (!(loss <= 1e20f)) loss = 0.0f;  // zero_infinity (inf/nan -> 0)
      int dv = (tl > 0) ? tl : 1;
      lossb[b] = loss / (float)dv;
    }
  }
}

// ---------------- K3: deterministic mean ---------------------------------
__global__ void k_mean(const float* __restrict__ lossb, float* __restrict__ out) {
  int lane = threadIdx.x;
  float v = (lane < B) ? lossb[lane] : 0.0f;
  for (int o = 32; o >= 1; o >>= 1) v += __shfl_xor(v, o, 64);
  if (lane == 0) out[0] = v / (float)B;
}

extern "C" void kernel_launch(void* const* d_in, const int* in_sizes, int n_in,
                              void* d_out, int out_size, void* d_ws, size_t ws_size,
                              hipStream_t stream) {
  const float* logits = (const float*)d_in[0];
  const int* targets = (const int*)d_in[1];
  const unsigned char* mask = (const unsigned char*)d_in[2];

  char* ws = (char*)d_ws;
  float* lossb = (float*)(ws + 128);             // [128,256)
  float* G = (float*)(ws + 512);                 // 32*1023 f32 = 131KB
  _Float16* E = (_Float16*)(ws + 512 + 132 * 1024);  // 32*1024*512 f16 = 33.5MB
  // k_ctc's deepest prefetch touches row 1024 of batch 31 (1KB past E);
  // ws (~512MB) is far larger than E+slack, so those reads stay in-bounds.

  k_emit<<<(B * TT) / 4, 256, 0, stream>>>(logits, targets, E, G);
  k_ctc<<<B, 64, 0, stream>>>(E, targets, mask, G, lossb);
  k_mean<<<1, 64, 0, stream>>>(lossb, (float*)d_out);
}

// Round 16
// 81.946 us; speedup vs baseline: 1.0363x; 1.0363x over previous
//
#include <hip/hip_runtime.h>

#define LOG2E 1.4426950408889634f
#define LN2   0.6931471805599453

static constexpr int B  = 32;
static constexpr int T  = 1024;   // original time length; we use rows 0..1022
static constexpr int TT = 1023;   // T-1
static constexpr int V  = 1000;
static constexpr int L  = 256;    // padded target length; labels used are cols 1..255
static constexpr int S  = 511;    // 2*255+1 extended states (valid s: 0..510)
static constexpr int LP = 256;    // label-probs per row in EL (fp16)
static constexpr int TP = 1024;   // padded rows per batch

using hf2 = __attribute__((ext_vector_type(2))) __fp16;   // cvt_pkrtz return type
using f4  = __attribute__((ext_vector_type(4))) float;
using i4  = __attribute__((ext_vector_type(4))) int;
using i2  = __attribute__((ext_vector_type(2))) int;

__device__ __forceinline__ float fexp2(float x) {
#if __has_builtin(__builtin_amdgcn_exp2f)
  return __builtin_amdgcn_exp2f(x);
#else
  return exp2f(x);
#endif
}
__device__ __forceinline__ float flog2(float x) {
#if __has_builtin(__builtin_amdgcn_logf)
  return __builtin_amdgcn_logf(x);   // v_log_f32 = log base 2
#else
  return log2f(x);
#endif
}

// ---- DPP helpers (VALU cross-lane; no LDS) ------------------------------
#if __has_builtin(__builtin_amdgcn_update_dpp)
// wave_shr1: lane i <- lane i-1; lane 0 <- 0 (bound_ctrl)
__device__ __forceinline__ float shr1f(float x) {
  int r = __builtin_amdgcn_update_dpp(0, __float_as_int(x), 0x138, 0xf, 0xf, true);
  return __int_as_float(r);
}
// wave_shl1: lane i <- lane i+1; lane 63 <- 0 (bound_ctrl)
__device__ __forceinline__ int shl1i(int x) {
  return __builtin_amdgcn_update_dpp(0, x, 0x130, 0xf, 0xf, true);
}
#define DPP_SWITCH(T, OLD, SRC, BC)                                            \
  T r;                                                                         \
  switch (ctrl) {                                                              \
    case 0x111: r = __builtin_amdgcn_update_dpp(OLD, SRC, 0x111, 0xf, 0xf, BC); break; \
    case 0x112: r = __builtin_amdgcn_update_dpp(OLD, SRC, 0x112, 0xf, 0xf, BC); break; \
    case 0x114: r = __builtin_amdgcn_update_dpp(OLD, SRC, 0x114, 0xf, 0xf, BC); break; \
    case 0x118: r = __builtin_amdgcn_update_dpp(OLD, SRC, 0x118, 0xf, 0xf, BC); break; \
    case 0x142: r = __builtin_amdgcn_update_dpp(OLD, SRC, 0x142, 0xf, 0xf, BC); break; \
    default:    r = __builtin_amdgcn_update_dpp(OLD, SRC, 0x143, 0xf, 0xf, BC); break; \
  }

// int max step, 0-identity (nonneg values only)
__device__ __forceinline__ int dppmax_step(int m, const int ctrl) {
  DPP_SWITCH(int, 0, m, true);
  return max(m, r);
}
__device__ __forceinline__ int wavemax_to_sgpr(int m) {
  m = dppmax_step(m, 0x111);
  m = dppmax_step(m, 0x112);
  m = dppmax_step(m, 0x114);
  m = dppmax_step(m, 0x118);
  m = dppmax_step(m, 0x142);
  m = dppmax_step(m, 0x143);
  return __builtin_amdgcn_readlane(m, 63);
}
// float max step, identity-free: invalid lanes keep old (=x) -> fmax(x,x)=x
__device__ __forceinline__ float dppfmax_step(float x, const int ctrl) {
  int xi = __float_as_int(x);
  DPP_SWITCH(int, xi, xi, false);
  return fmaxf(x, __int_as_float(r));
}
__device__ __forceinline__ float wavefmax(float x) {
  x = dppfmax_step(x, 0x111);
  x = dppfmax_step(x, 0x112);
  x = dppfmax_step(x, 0x114);
  x = dppfmax_step(x, 0x118);
  x = dppfmax_step(x, 0x142);
  x = dppfmax_step(x, 0x143);
  return __int_as_float(__builtin_amdgcn_readlane(__float_as_int(x), 63));
}
// float add step, 0-identity
__device__ __forceinline__ float dppfadd_step(float x, const int ctrl) {
  DPP_SWITCH(int, 0, __float_as_int(x), true);
  return x + __int_as_float(r);
}
__device__ __forceinline__ float wavefsum(float x) {
  x = dppfadd_step(x, 0x111);
  x = dppfadd_step(x, 0x112);
  x = dppfadd_step(x, 0x114);
  x = dppfadd_step(x, 0x118);
  x = dppfadd_step(x, 0x142);
  x = dppfadd_step(x, 0x143);
  return __int_as_float(__builtin_amdgcn_readlane(__float_as_int(x), 63));
}
#else
__device__ __forceinline__ float shr1f(float x) {
  float r = __shfl_up(x, 1, 64);
  return (threadIdx.x & 63) == 0 ? 0.0f : r;
}
__device__ __forceinline__ int shl1i(int x) {
  int r = __shfl_down(x, 1, 64);
  return (threadIdx.x & 63) == 63 ? 0 : r;
}
__device__ __forceinline__ int wavemax_to_sgpr(int m) {
  for (int o = 32; o >= 1; o >>= 1) m = max(m, __shfl_xor(m, o, 64));
  return m;
}
__device__ __forceinline__ float wavefmax(float x) {
  for (int o = 32; o >= 1; o >>= 1) x = fmaxf(x, __shfl_xor(x, o, 64));
  return x;
}
__device__ __forceinline__ float wavefsum(float x) {
  for (int o = 32; o >= 1; o >>= 1) x += __shfl_xor(x, o, 64);
  return x;
}
#endif

// ---- target length from padding mask (byte-bool vs int32 hedge) ---------
__device__ __forceinline__ int mask_tlen(const unsigned char* maskb, int b, int lane) {
  int ca = 0;
  for (int k = lane; k < L; k += 64) ca += (maskb[b * L + k] != 0) ? 1 : 0;
  for (int o = 32; o >= 1; o >>= 1) ca += __shfl_xor(ca, o, 64);
  int cnt = ca;
  if (ca < 130) {  // wave-uniform: layout must be int32
    const int* mi = (const int*)maskb;
    int cb = 0;
    for (int k = lane; k < L; k += 64) cb += (mi[b * L + k] != 0) ? 1 : 0;
    for (int o = 32; o >= 1; o >>= 1) cb += __shfl_xor(cb, o, 64);
    cnt = cb;
  }
  return cnt - 1;
}

// ---------------- K1: wave-per-row softmax-scale + compact emit ----------
// One WAVE per (b,t) row. Compact layout: EL[b][t] = 256 label probs (fp16,
// lane l holds labels 4l+1..4l+4 as {e1,e2},{e3,e4}); EB[b][t-1] = blank
// prob (fp16, offset -1 so ctc's 8-row groups at t=1+8k are 16B-aligned);
// I2[2b..2b+1] = f32 {blank(0), e1(0)} for the alpha init.
// G[r] = rowmax*log2e - lse2.
__global__ __launch_bounds__(256) void k_emit(const float* __restrict__ logits,
                                              const int* __restrict__ targets,
                                              _Float16* __restrict__ EL,
                                              _Float16* __restrict__ EBs,
                                              float* __restrict__ I2,
                                              float* __restrict__ G) {
  __shared__ float yrow[4][1024];  // 16KB: per-wave private raw-logit row
  const int wid = threadIdx.x >> 6;
  const int lane = threadIdx.x & 63;
  float* yw = yrow[wid];
  const int r = blockIdx.x * 4 + wid;   // B*TT = 32736 = 8184 * 4 exactly
  const int b = r / TT;
  const int t = r - b * TT;

  const f4* row = reinterpret_cast<const f4*>(logits + ((size_t)b * T + t) * V);
  f4 u0 = row[lane];
  f4 u1 = row[lane + 64];
  f4 u2 = row[lane + 128];
  const bool has3 = (lane < 58);  // 1000 = 250 float4
  f4 u3;
  if (has3) u3 = row[lane + 192];
  else { u3[0] = u3[1] = u3[2] = u3[3] = -3.0e38f; }

  reinterpret_cast<f4*>(yw)[lane]       = u0;
  reinterpret_cast<f4*>(yw)[lane + 64]  = u1;
  reinterpret_cast<f4*>(yw)[lane + 128] = u2;
  if (has3) reinterpret_cast<f4*>(yw)[lane + 192] = u3;

  float lm = fmaxf(fmaxf(fmaxf(u0[0], u0[1]), fmaxf(u0[2], u0[3])),
                   fmaxf(fmaxf(u1[0], u1[1]), fmaxf(u1[2], u1[3])));
  lm = fmaxf(lm, fmaxf(fmaxf(u2[0], u2[1]), fmaxf(u2[2], u2[3])));
  lm = fmaxf(lm, fmaxf(fmaxf(u3[0], u3[1]), fmaxf(u3[2], u3[3])));
  const float my = wavefmax(lm);        // raw-domain row max (uniform)
  const float c = -my * LOG2E;          // exp2(x*LOG2E + c) = 2^((x-my)*log2e)

  float ps = fexp2(fmaf(u0[0], LOG2E, c)) + fexp2(fmaf(u0[1], LOG2E, c))
           + fexp2(fmaf(u0[2], LOG2E, c)) + fexp2(fmaf(u0[3], LOG2E, c))
           + fexp2(fmaf(u1[0], LOG2E, c)) + fexp2(fmaf(u1[1], LOG2E, c))
           + fexp2(fmaf(u1[2], LOG2E, c)) + fexp2(fmaf(u1[3], LOG2E, c))
           + fexp2(fmaf(u2[0], LOG2E, c)) + fexp2(fmaf(u2[1], LOG2E, c))
           + fexp2(fmaf(u2[2], LOG2E, c)) + fexp2(fmaf(u2[3], LOG2E, c))
           + fexp2(fmaf(u3[0], LOG2E, c)) + fexp2(fmaf(u3[1], LOG2E, c))
           + fexp2(fmaf(u3[2], LOG2E, c)) + fexp2(fmaf(u3[3], LOG2E, c));
  const float g = -flog2(wavefsum(ps)); // rowmax - lse (log2 domain)

  // gather: lane l -> labels 4l+1..4l+4 (int4 + DPP shl)
  const int base = b * L + (lane << 2);
  i4 tv = *reinterpret_cast<const i4*>(targets + base);  // 16B-aligned
  const int l1 = tv[1], l2 = tv[2], l3 = tv[3];
  const int l4 = shl1i(tv[0]);          // label 4l+4 from lane+1; lane63 -> 0
  const float eb = fexp2(fmaf(yw[0],  LOG2E, c));
  const float e1 = fexp2(fmaf(yw[l1], LOG2E, c));
  const float e2 = fexp2(fmaf(yw[l2], LOG2E, c));
  const float e3 = fexp2(fmaf(yw[l3], LOG2E, c));
  float e4       = fexp2(fmaf(yw[l4], LOG2E, c));
  if (lane == 63) e4 = 0.0f;            // state 511 (dead) must be 0

  i2 oi;
#if __has_builtin(__builtin_amdgcn_cvt_pkrtz)
  { hf2 p = __builtin_amdgcn_cvt_pkrtz(e1, e2); oi[0] = __builtin_bit_cast(int, p); }
  { hf2 p = __builtin_amdgcn_cvt_pkrtz(e3, e4); oi[1] = __builtin_bit_cast(int, p); }
#else
  { hf2 p; p[0] = (__fp16)e1; p[1] = (__fp16)e2; oi[0] = __builtin_bit_cast(int, p); }
  { hf2 p; p[0] = (__fp16)e3; p[1] = (__fp16)e4; oi[1] = __builtin_bit_cast(int, p); }
#endif
  reinterpret_cast<i2*>(EL + ((size_t)b * TP + t) * LP)[lane] = oi;
  if (lane == 0) {
    G[r] = g;
    if (t > 0) EBs[b * TP + (t - 1)] = (_Float16)eb;
    else { I2[2 * b] = eb; I2[2 * b + 1] = e1; }
  }
}

// ---------------- K2: CTC alpha recurrence, f32 prob domain --------------
// One wave per batch; lane l owns states 8l..8l+7. Compact E: per row one
// dwordx2 of label probs/lane + broadcast blank (dwordx4 = 8 rows' blanks).
// v_fma_mix_f32 consumes fp16 halves directly. 4 buffers x 8 rows, counted
// s_waitcnt vmcnt(27) (9 loads/group). Exact pow2 rescale (VALID-state wave
// max -> 2^64) every 32 steps; invalid states masked out of the max.
__global__ __launch_bounds__(64, 1) void k_ctc(const _Float16* __restrict__ EL,
                                               const _Float16* __restrict__ EBs,
                                               const int* __restrict__ targets,
                                               const unsigned char* __restrict__ maskb,
                                               const float* __restrict__ G,
                                               const float* __restrict__ I2,
                                               float* __restrict__ lossb) {
  const int b = blockIdx.x;
  const int lane = threadIdx.x;
  const int s0 = lane << 3;
  const int* tg = targets + b * L;

  const int tl = mask_tlen(maskb, b, lane);

  // skip-allowed multipliers for odd states (1.0f or 0.0f)
  float f1 = 0.0f, f3, f5, f7 = 0.0f;
  {
    int s = s0 + 1;
    if (s >= 3) f1 = (tg[(s + 1) >> 1] != tg[(s - 1) >> 1]) ? 1.0f : 0.0f;
    s = s0 + 3;
    f3 = (tg[(s + 1) >> 1] != tg[(s - 1) >> 1]) ? 1.0f : 0.0f;
    s = s0 + 5;
    f5 = (tg[(s + 1) >> 1] != tg[(s - 1) >> 1]) ? 1.0f : 0.0f;
    s = s0 + 7;
    if (s < S) f7 = (tg[(s + 1) >> 1] != tg[(s - 1) >> 1]) ? 1.0f : 0.0f;
  }

  // validity masks for the rescale max: state s0+i valid iff s0+i <= 2*tl
  const int s2t = 2 * tl;
  const int vm0 = (s0 + 0 <= s2t) ? -1 : 0;
  const int vm1 = (s0 + 1 <= s2t) ? -1 : 0;
  const int vm2 = (s0 + 2 <= s2t) ? -1 : 0;
  const int vm3 = (s0 + 3 <= s2t) ? -1 : 0;
  const int vm4 = (s0 + 4 <= s2t) ? -1 : 0;
  const int vm5 = (s0 + 5 <= s2t) ? -1 : 0;
  const int vm6 = (s0 + 6 <= s2t) ? -1 : 0;
  const int vm7 = (s0 + 7 <= s2t) ? -1 : 0;

  const _Float16* ELb = EL + (size_t)b * TP * LP + (lane << 2);  // row r: +r*256
  const _Float16* EBb = EBs + b * TP;                            // blank(t)=EBb[t-1]

  // alpha init from t=0: only s=0,1 live
  float a0 = (lane == 0) ? I2[2 * b]     : 0.0f;
  float a1 = (lane == 0) ? I2[2 * b + 1] : 0.0f;
  float a2 = 0.f, a3 = 0.f, a4 = 0.f, a5 = 0.f, a6 = 0.f, a7 = 0.f;
  float n7 = 0.0f;  // a7 of lane-1, pipelined across steps
  int lsacc = 0;

  // Force all compiler-issued loads (mask, tg flags, I2) to complete NOW so
  // the compiler never inserts its own s_waitcnt vmcnt(0) in the loop.
  asm volatile("" :: "v"(f1), "v"(f3), "v"(f5), "v"(f7),
                     "v"(a0), "v"(a1), "v"((float)tl));

// one group = 8 rows: 8 x dwordx2 labels (row stride 512B) + 1 x dwordx4
// broadcast blanks (EBs, 16B-aligned since r0 = 1+8k). 9 loads.
#define LOAD8(P, r0)                                             \
  do {                                                           \
    const _Float16* ql_ = ELb + (size_t)(r0) * LP;               \
    const _Float16* qb_ = EBb + ((r0) - 1);                      \
    asm volatile(                                                \
      "global_load_dwordx2 %0, %9, off\n\t"                      \
      "global_load_dwordx2 %1, %9, off offset:512\n\t"           \
      "global_load_dwordx2 %2, %9, off offset:1024\n\t"          \
      "global_load_dwordx2 %3, %9, off offset:1536\n\t"          \
      "global_load_dwordx2 %4, %9, off offset:2048\n\t"          \
      "global_load_dwordx2 %5, %9, off offset:2560\n\t"          \
      "global_load_dwordx2 %6, %9, off offset:3072\n\t"          \
      "global_load_dwordx2 %7, %9, off offset:3584\n\t"          \
      "global_load_dwordx4 %8, %10, off"                         \
      : "=&v"(P##0), "=&v"(P##1), "=&v"(P##2), "=&v"(P##3),      \
        "=&v"(P##4), "=&v"(P##5), "=&v"(P##6), "=&v"(P##7),      \
        "=&v"(P##Q)                                              \
      : "v"(ql_), "v"(qb_));                                     \
  } while (0)

// counted wait; redefines buffer P's registers so uses can't precede it
#define VMWAIT8(n, P)                                            \
  do {                                                           \
    asm volatile("s_waitcnt vmcnt(" #n ")"                       \
                 : "+v"(P##0), "+v"(P##1), "+v"(P##2), "+v"(P##3), \
                   "+v"(P##4), "+v"(P##5), "+v"(P##6), "+v"(P##7), \
                   "+v"(P##Q));                                  \
    __builtin_amdgcn_sched_barrier(0);                           \
  } while (0)

// fused f16->f32 convert + multiply: D = s * f16(half of HWORD) + 0
#define MIXLO(D, SSS, HWORD)                                     \
  asm("v_fma_mix_f32 %0, %1, %2, 0 op_sel:[0,0,0] op_sel_hi:[0,1,0]" \
      : "=v"(D) : "v"(SSS), "v"(HWORD))
#define MIXHI(D, SSS, HWORD)                                     \
  asm("v_fma_mix_f32 %0, %1, %2, 0 op_sel:[0,1,0] op_sel_hi:[0,1,0]" \
      : "=v"(D) : "v"(SSS), "v"(HWORD))

// One step. H = i2 label packet {e1,e2},{e3,e4}; BD = blank dword; BMIX
// selects which half of BD holds this row's blank. t7 first (pipelined DPP).
#define STEP_IMPL(H, BD, BMIX)                                  \
  do {                                                          \
    float s7_ = fmaf(f7, a5, a6 + a7);                          \
    float t7; MIXHI(t7, s7_, (H)[1]);     /* e4 */              \
    float n7n = shr1f(t7);                                      \
    float s0_ = a0 + n7;                                        \
    float s1_ = fmaf(f1, n7, a0 + a1);                          \
    float s2_ = a1 + a2;                                        \
    float s3_ = fmaf(f3, a1, a2 + a3);                          \
    float s4_ = a3 + a4;                                        \
    float s5_ = fmaf(f5, a3, a4 + a5);                          \
    float s6_ = a5 + a6;                                        \
    float t0, t1, t2, t3, t4, t5, t6;                           \
    BMIX(t0, s0_, (BD));                  /* blank */           \
    MIXLO(t1, s1_, (H)[0]);               /* e1 */              \
    BMIX(t2, s2_, (BD));                                        \
    MIXHI(t3, s3_, (H)[0]);               /* e2 */              \
    BMIX(t4, s4_, (BD));                                        \
    MIXLO(t5, s5_, (H)[1]);               /* e3 */              \
    BMIX(t6, s6_, (BD));                                        \
    a0 = t0; a1 = t1; a2 = t2; a3 = t3;                         \
    a4 = t4; a5 = t5; a6 = t6; a7 = t7;                         \
    n7 = n7n;                                                   \
  } while (0)
#define STEPFL(H, BD) STEP_IMPL(H, BD, MIXLO)
#define STEPFH(H, BD) STEP_IMPL(H, BD, MIXHI)

// exact pow2 rescale: VALID-state wave-max alpha -> 2^64, every 32 steps.
// Growth <= 3^32 ~ 2^50.7; 2^64 * 2^51 < 2^127 (no overflow of valid
// states). Underflow window: 64+149 = 213 log2 below the valid max.
#define RESCALE()                                               \
  do {                                                          \
    int m = max(max(max(__float_as_int(a0) & vm0,               \
                        __float_as_int(a1) & vm1),              \
                    max(__float_as_int(a2) & vm2,               \
                        __float_as_int(a3) & vm3)),             \
                max(max(__float_as_int(a4) & vm4,               \
                        __float_as_int(a5) & vm5),              \
                    max(__float_as_int(a6) & vm6,               \
                        __float_as_int(a7) & vm7)));            \
    int mw = wavemax_to_sgpr(m);                                \
    int e = mw >> 23;                                           \
    int sh = 191 - e;                                           \
    lsacc += e - 191;                                           \
    a0 = ldexpf(a0, sh); a1 = ldexpf(a1, sh);                   \
    a2 = ldexpf(a2, sh); a3 = ldexpf(a3, sh);                   \
    a4 = ldexpf(a4, sh); a5 = ldexpf(a5, sh);                   \
    a6 = ldexpf(a6, sh); a7 = ldexpf(a7, sh);                   \
    n7 = ldexpf(n7, sh);                                        \
  } while (0)

#define PROC8(P)                                                \
  do {                                                          \
    STEPFL(P##0, P##Q[0]); STEPFH(P##1, P##Q[0]);               \
    STEPFL(P##2, P##Q[1]); STEPFH(P##3, P##Q[1]);               \
    STEPFL(P##4, P##Q[2]); STEPFH(P##5, P##Q[2]);               \
    STEPFL(P##6, P##Q[3]); STEPFH(P##7, P##Q[3]);               \
  } while (0)

  i2 A0, A1, A2, A3, A4, A5, A6, A7; i4 AQ;
  i2 B0, B1, B2, B3, B4, B5, B6, B7; i4 BQ;
  i2 C0, C1, C2, C3, C4, C5, C6, C7; i4 CQ;
  i2 D0, D1, D2, D3, D4, D5, D6, D7; i4 DQ;

  LOAD8(A, 1);    // rows 1..8     (9 loads)
  LOAD8(B, 9);    // rows 9..16    (18)
  LOAD8(C, 17);   // rows 17..24   (27)
  LOAD8(D, 25);   // rows 25..32   (36 outstanding)

  int t = 1;
#pragma unroll 1
  for (int it = 0; it < 30; ++it) {   // 30 * 32 = 960 rows: t = 1 .. 960
    RESCALE();                        // once per 32 steps
    VMWAIT8(27, A); PROC8(A); LOAD8(A, t + 32);
    VMWAIT8(27, B); PROC8(B); LOAD8(B, t + 40);
    VMWAIT8(27, C); PROC8(C); LOAD8(C, t + 48);
    VMWAIT8(27, D); PROC8(D); LOAD8(D, t + 56);
    t += 32;
  }
  // t = 961. Buffers: A=961..968, B=969..976, C=977..984, D=985..992.
  RESCALE();
  VMWAIT8(27, A); PROC8(A); LOAD8(A, 993);    // load 993..1000
  VMWAIT8(27, B); PROC8(B); LOAD8(B, 1001);   // load 1001..1008
  VMWAIT8(27, C); PROC8(C); LOAD8(C, 1009);   // load 1009..1016
  VMWAIT8(27, D); PROC8(D); LOAD8(D, 1017);   // load 1017..1024
  RESCALE();                                  // covers remaining 30 rows
  VMWAIT8(27, A); PROC8(A);                   // rows 993..1000
  VMWAIT8(18, B); PROC8(B);                   // rows 1001..1008
  VMWAIT8(9,  C); PROC8(C);                   // rows 1009..1016
  VMWAIT8(0,  D);
  STEPFL(D0, DQ[0]); STEPFH(D1, DQ[0]);
  STEPFL(D2, DQ[1]); STEPFH(D3, DQ[1]);
  STEPFL(D4, DQ[2]); STEPFH(D5, DQ[2]);       // rows 1017..1022
#undef LOAD8
#undef VMWAIT8
#undef MIXLO
#undef MIXHI
#undef STEP_IMPL
#undef STEPFL
#undef STEPFH
#undef RESCALE
#undef PROC8

  // per-batch sum of G (deterministic fixed tree, f64) — epilogue so its
  // loads never interfere with the loop's vmcnt counts.
  double gs = 0.0;
  for (int k = lane; k < TT; k += 64) gs += (double)G[b * TT + k];
  for (int o = 32; o >= 1; o >>= 1) gs += __shfl_xor(gs, o, 64);

  // epilogue: pick states i1 and i1-1 via uniform reg-switch + shfl
  {
    int i1 = 2 * tl;
    int j1 = (i1 > 0 ? i1 : 1) - 1;
    float va, vb;
    switch (i1 & 7) {   // tl is wave-uniform -> uniform branch
      case 0: va = a0; break; case 1: va = a1; break;
      case 2: va = a2; break; case 3: va = a3; break;
      case 4: va = a4; break; case 5: va = a5; break;
      case 6: va = a6; break; default: va = a7; break;
    }
    switch (j1 & 7) {
      case 0: vb = a0; break; case 1: vb = a1; break;
      case 2: vb = a2; break; case 3: vb = a3; break;
      case 4: vb = a4; break; case 5: vb = a5; break;
      case 6: vb = a6; break; default: vb = a7; break;
    }
    float l1v = __shfl(va, i1 >> 3, 64);
    float l2v = __shfl(vb, j1 >> 3, 64);
    if (lane == 0) {
      float p = l1v + l2v;
      int hi = __float_as_int(p);
      int ep = (hi >> 23) - 127;
      float pm = ldexpf(p, -ep);          // in [1,2) for normal p
      float lm = flog2(pm);
      double loss2 = -((double)lm + (double)ep + (double)lsacc + gs);
      float loss = (float)(loss2 * LN2);  // back to natural log
      if (!(loss <= 1e20f)) loss = 0.0f;  // zero_infinity (inf/nan -> 0)
      int dv = (tl > 0) ? tl : 1;
      lossb[b] = loss / (float)dv;
    }
  }
}

// ---------------- K3: deterministic mean ---------------------------------
__global__ void k_mean(const float* __restrict__ lossb, float* __restrict__ out) {
  int lane = threadIdx.x;
  float v = (lane < B) ? lossb[lane] : 0.0f;
  for (int o = 32; o >= 1; o >>= 1) v += __shfl_xor(v, o, 64);
  if (lane == 0) out[0] = v / (float)B;
}

extern "C" void kernel_launch(void* const* d_in, const int* in_sizes, int n_in,
                              void* d_out, int out_size, void* d_ws, size_t ws_size,
                              hipStream_t stream) {
  const float* logits = (const float*)d_in[0];
  const int* targets = (const int*)d_in[1];
  const unsigned char* mask = (const unsigned char*)d_in[2];

  char* ws = (char*)d_ws;
  float* lossb = (float*)(ws + 128);                 // 32 f32
  float* I2 = (float*)(ws + 256);                    // 64 f32 (init pairs)
  float* G = (float*)(ws + 512);                     // 32*1023 f32 = 131KB
  _Float16* EBs = (_Float16*)(ws + 140 * 1024);      // 32*1024 fp16 = 64KB
  _Float16* EL = (_Float16*)(ws + 256 * 1024);       // 32*1024*256 fp16 = 16.8MB
  // k_ctc's deepest prefetch touches EL row 1024 of batch 31 (512B past EL)
  // and EBs index 1023 (in-bounds); ws is far larger, so reads stay in d_ws.

  k_emit<<<(B * TT) / 4, 256, 0, stream>>>(logits, targets, EL, EBs, I2, G);
  k_ctc<<<B, 64, 0, stream>>>(EL, EBs, targets, mask, G, I2, lossb);
  k_mean<<<1, 64, 0, stream>>>(lossb, (float*)d_out);
}